// Round 4
// baseline (268.296 us; speedup 1.0000x reference)
//
#include <hip/hip_runtime.h>

// FiniteDifference: x[B=4,T=16,H=128,W=128,C=16] f32
// out = (dy along H, dx along W, dz along T), each = x[i+1]-x[i-1] (zero "same" pad).
// Strides in floats: c:1, w:16, h:2048, t:262144, b:4194304.
// Each thread: one float4 (4 channels), all 3 outputs. NT stores (write-once).
// R4: XCD-chunk block swizzle (T1). Default bid%8 round-robin puts the
// H-neighbor reuse (+-2 blocks) on a different XCD's L2; contiguous 2048-block
// chunks per XCD keep all H/T stencil reuse XCD-local. 16384 % 8 == 0 -> the
// simple bijective form is valid.

typedef float f32x4 __attribute__((ext_vector_type(4)));

#define N_TOTAL (4 * 16 * 128 * 128 * 16)  // 16,777,216 elements
#define TOT4 (N_TOTAL / 4)                 // 4,194,304 float4s (grid divides exactly)
#define NBLK (TOT4 / 256)                  // 16384 blocks
#define CHUNK (NBLK / 8)                   // 2048 blocks per XCD

__global__ __launch_bounds__(256) void fd3_kernel(
    const f32x4* __restrict__ x,
    f32x4* __restrict__ dy,   // d/dH
    f32x4* __restrict__ dx,   // d/dW
    f32x4* __restrict__ dz)   // d/dT
{
    // float4 strides: W: 4, H: 512, T: 65536
    constexpr int SW = 4;
    constexpr int SH = 512;
    constexpr int ST = 65536;

    // XCD-aware swizzle: XCD k (= bid%8 hardware round-robin) handles the
    // contiguous block range [k*CHUNK, (k+1)*CHUNK).
    const int bid  = blockIdx.x;
    const int swz  = (bid & 7) * CHUNK + (bid >> 3);
    const int i    = swz * 256 + threadIdx.x;

    // decompose float4 index: [b(2)][t(4)][h(7)][w(7)][c4(2)]
    const int w = (i >> 2) & 127;
    const int h = (i >> 9) & 127;
    const int t = (i >> 16) & 15;

    const f32x4 z = (f32x4)(0.f);

    const f32x4 wm = (w > 0)   ? x[i - SW] : z;
    const f32x4 wp = (w < 127) ? x[i + SW] : z;
    const f32x4 hm = (h > 0)   ? x[i - SH] : z;
    const f32x4 hp = (h < 127) ? x[i + SH] : z;
    const f32x4 tm = (t > 0)   ? x[i - ST] : z;
    const f32x4 tp = (t < 15)  ? x[i + ST] : z;

    __builtin_nontemporal_store(hp - hm, &dy[i]);
    __builtin_nontemporal_store(wp - wm, &dx[i]);
    __builtin_nontemporal_store(tp - tm, &dz[i]);
}

extern "C" void kernel_launch(void* const* d_in, const int* in_sizes, int n_in,
                              void* d_out, int out_size, void* d_ws, size_t ws_size,
                              hipStream_t stream) {
    const f32x4* x = (const f32x4*)d_in[0];
    float* out = (float*)d_out;
    f32x4* dy = (f32x4*)(out);                 // reference returns (dy, dx, dz)
    f32x4* dx = (f32x4*)(out + N_TOTAL);
    f32x4* dz = (f32x4*)(out + 2 * (size_t)N_TOTAL);

    const int threads = 256;
    fd3_kernel<<<NBLK, threads, 0, stream>>>(x, dy, dx, dz);
}